// Round 5
// baseline (67.846 us; speedup 1.0000x reference)
//
#include <hip/hip_runtime.h>

#define E_TOTAL 320000
#define NNODES  10000
#define HID     256
#define NCLS    10

typedef __attribute__((ext_vector_type(4))) float f32x4;
typedef __attribute__((ext_vector_type(4))) unsigned int u32x4;
typedef __attribute__((ext_vector_type(8))) __bf16 bf16x8;
typedef __attribute__((ext_vector_type(8))) unsigned short u16x8;

static __device__ __forceinline__ unsigned short f2bf(float f) {
  unsigned u = __builtin_bit_cast(unsigned, f);
  u += 0x7fffu + ((u >> 16) & 1u);
  return (unsigned short)(u >> 16);
}

// ---- merged prep: x->bf16 | W1->frag | W2->frag, split by blockIdx ----
__global__ void k_pack(const float* __restrict__ x,
                       const float* __restrict__ W1,
                       const float* __restrict__ W2,
                       unsigned short* __restrict__ xbf,
                       unsigned short* __restrict__ w1f,
                       unsigned short* __restrict__ w2f) {
  int b = blockIdx.x, tid = threadIdx.x;
  if (b < 1250) {
    int i = b * 256 + tid;                        // one thread per 8 elems
    const f32x4* s = (const f32x4*)x + (size_t)i * 2;
    f32x4 a = s[0], c = s[1];
    u16x8 o;
    o[0]=f2bf(a[0]); o[1]=f2bf(a[1]); o[2]=f2bf(a[2]); o[3]=f2bf(a[3]);
    o[4]=f2bf(c[0]); o[5]=f2bf(c[1]); o[6]=f2bf(c[2]); o[7]=f2bf(c[3]);
    *((u16x8*)xbf + i) = o;
  } else if (b < 1314) {
    int gid = (b - 1250) * 256 + tid;             // 16384
    int l = gid & 63, kk = (gid >> 6) & 7, cb = (gid >> 9) & 15, half = gid >> 13;
    int kbase = half * 256 + kk * 32 + (l >> 4) * 8;
    int col = cb * 16 + (l & 15);
    u16x8 o;
#pragma unroll
    for (int j = 0; j < 8; ++j) o[j] = f2bf(W1[(size_t)(kbase + j) * HID + col]);
    *((u16x8*)w1f + gid) = o;
  } else {
    int gid = (b - 1314) * 256 + tid;             // 512
    int l = gid & 63, kk = gid >> 6;
    int kbase = kk * 32 + (l >> 4) * 8;
    int c = l & 15;
    u16x8 o;
#pragma unroll
    for (int j = 0; j < 8; ++j)
      o[j] = (c < NCLS) ? f2bf(W2[(size_t)(kbase + j) * NCLS + c]) : (unsigned short)0;
    *((u16x8*)w2f + gid) = o;
  }
}

// ---- node GEMM: Y[n][half*256+col] = sum_k x[n][k]*W1[half*256+k][col] (+b1 if half==0)
__global__ __launch_bounds__(256, 3) void k_prep(
    const unsigned short* __restrict__ xbf,
    const unsigned short* __restrict__ w1f,
    const float* __restrict__ b1,
    unsigned short* __restrict__ Y)           // [NNODES][512] bf16
{
  __shared__ __align__(16) unsigned short ldsA[2][32 * 64];  // XOR-swizzled tiles

  const int tid  = threadIdx.x;
  const int lane = tid & 63;
  const int wv   = tid >> 6;
  const int n0   = blockIdx.x * 32;
  const int half = blockIdx.y;
  const int l15  = lane & 15;
  const int lhi  = lane >> 4;

  f32x4 acc[2][4] = {};

  auto stageA = [&](int kb, int buf) {
    int col0 = kb * 64;
    int r = wv * 8 + (lane >> 3);
    int gr = n0 + r; if (gr > NNODES - 1) gr = NNODES - 1;
    int usrc = (lane & 7) ^ (r & 7);
    const unsigned short* g = xbf + (size_t)gr * HID + col0 + usrc * 8;
    unsigned short* lp = &ldsA[buf][(wv * 8) * 64];
    __builtin_amdgcn_global_load_lds(
        (const __attribute__((address_space(1))) unsigned int*)g,
        (__attribute__((address_space(3))) unsigned int*)lp,
        16, 0, 0);
  };

  stageA(0, 0);

  for (int kb = 0; kb < 4; ++kb) {
    int buf = kb & 1;
    __syncthreads();
    if (kb < 3) stageA(kb + 1, buf ^ 1);

    bf16x8 bfr[2][4];
#pragma unroll
    for (int ks = 0; ks < 2; ++ks)
#pragma unroll
      for (int n = 0; n < 4; ++n) {
        int cb = wv * 4 + n;
        int kk = kb * 2 + ks;
        int f = (half * 16 + cb) * 8 + kk;
        bfr[ks][n] = *(const bf16x8*)(w1f + ((size_t)f * 64 + lane) * 8);
      }

#pragma unroll
    for (int ks = 0; ks < 2; ++ks) {
      bf16x8 afr[2];
#pragma unroll
      for (int m = 0; m < 2; ++m) {
        int row = m * 16 + l15;
        int boff = row * 128 + ((ks * 64 + lhi * 16) ^ ((row & 7) << 4));
        afr[m] = *(const bf16x8*)((const char*)&ldsA[buf][0] + boff);
      }
#pragma unroll
      for (int m = 0; m < 2; ++m)
#pragma unroll
        for (int n = 0; n < 4; ++n)
          acc[m][n] = __builtin_amdgcn_mfma_f32_16x16x32_bf16(afr[m], bfr[ks][n], acc[m][n], 0, 0, 0);
    }
  }

  float b1v[4];
#pragma unroll
  for (int n = 0; n < 4; ++n) b1v[n] = (half == 0) ? b1[wv * 64 + n * 16 + l15] : 0.f;

#pragma unroll
  for (int m = 0; m < 2; ++m)
#pragma unroll
    for (int n = 0; n < 4; ++n)
#pragma unroll
      for (int r = 0; r < 4; ++r) {
        int row = m * 16 + lhi * 4 + r;
        int col = wv * 64 + n * 16 + l15;
        int gr = n0 + row;
        if (gr < NNODES)
          Y[(size_t)gr * 512 + half * 256 + col] = f2bf(acc[m][n][r] + b1v[n]);
      }
}

// issue one 16B global load via volatile asm (ordered, result pinned in VGPRs)
#define GLD(dst, ptr, off) \
  asm volatile("global_load_dwordx4 %0, %1, off offset:" #off \
               : "=v"(dst) : "v"(ptr))

// ---- edge kernel: gather Y1[src]+Y2[dst], relu, GEMM2 (K=256,N=16pad), log_softmax
// Wave handles 16 edges; all 16 gathers forced in flight via volatile-asm loads.
__global__ __launch_bounds__(256, 3) void k_edge(
    const int* __restrict__ ei,
    const unsigned short* __restrict__ Y,
    const unsigned short* __restrict__ w2f,
    const float* __restrict__ b2,
    float* __restrict__ out)
{
  __shared__ __align__(16) unsigned short ldsW[4096];   // w2 frags, 8 KB

  const int tid  = threadIdx.x;
  const int lane = tid & 63;
  const int wv   = tid >> 6;
  const int e0   = blockIdx.x * 64;
  const int l15  = lane & 15;
  const int lhi  = lane >> 4;

  int edge = e0 + wv * 16 + l15;
  int src = ei[edge];
  int dst = ei[E_TOTAL + edge];

  // stage w2f -> LDS (before gathers; barrier drains vmcnt here, cheap)
  {
    const u16x8* s = (const u16x8*)w2f;
    u16x8* d = (u16x8*)ldsW;
    d[tid] = s[tid];
    d[tid + 256] = s[tid + 256];
  }
  __syncthreads();

  const unsigned short* p1 = Y + (size_t)src * 512 + lhi * 8;
  const unsigned short* p2 = Y + (size_t)dst * 512 + 256 + lhi * 8;

  // 16 loads issued back-to-back (volatile asm order is preserved; results
  // must stay in distinct VGPRs until consumed after the waitcnt)
  u32x4 ya[8], yb[8];
  GLD(ya[0], p1, 0);   GLD(ya[1], p1, 64);  GLD(ya[2], p1, 128); GLD(ya[3], p1, 192);
  GLD(ya[4], p1, 256); GLD(ya[5], p1, 320); GLD(ya[6], p1, 384); GLD(ya[7], p1, 448);
  GLD(yb[0], p2, 0);   GLD(yb[1], p2, 64);  GLD(yb[2], p2, 128); GLD(yb[3], p2, 192);
  GLD(yb[4], p2, 256); GLD(yb[5], p2, 320); GLD(yb[6], p2, 384); GLD(yb[7], p2, 448);
  asm volatile("s_waitcnt vmcnt(0)" ::: "memory");
  __builtin_amdgcn_sched_barrier(0);   // rule #18: nothing hoists above the wait

  f32x4 lg = {0.f, 0.f, 0.f, 0.f};
#pragma unroll
  for (int kk = 0; kk < 8; ++kk) {
    bf16x8 bw = *(const bf16x8*)(ldsW + kk * 512 + lane * 8);
    bf16x8 a = __builtin_bit_cast(bf16x8, ya[kk]);
    bf16x8 b = __builtin_bit_cast(bf16x8, yb[kk]);
    bf16x8 hh;
#pragma unroll
    for (int j = 0; j < 8; ++j) {
      float v = (float)a[j] + (float)b[j];
      hh[j] = (__bf16)fmaxf(v, 0.f);
    }
    lg = __builtin_amdgcn_mfma_f32_16x16x32_bf16(hh, bw, lg, 0, 0, 0);
  }

  // + b2, log_softmax across the 16-lane class group (cols 10..15 padding)
  bool valid = (l15 < NCLS);
  float bias = valid ? b2[l15] : 0.f;
#pragma unroll
  for (int r = 0; r < 4; ++r) {
    float v = lg[r] + bias;
    float mv = valid ? v : -1e30f;
#pragma unroll
    for (int s = 1; s < 16; s <<= 1) mv = fmaxf(mv, __shfl_xor(mv, s, 64));
    float ev = valid ? __expf(v - mv) : 0.f;
    float sv = ev;
#pragma unroll
    for (int s = 1; s < 16; s <<= 1) sv += __shfl_xor(sv, s, 64);
    float res = v - mv - __logf(sv);
    if (valid) out[(size_t)(e0 + wv * 16 + lhi * 4 + r) * NCLS + l15] = res;
  }
}

extern "C" void kernel_launch(void* const* d_in, const int* in_sizes, int n_in,
                              void* d_out, int out_size, void* d_ws, size_t ws_size,
                              hipStream_t stream) {
  const float* x  = (const float*)d_in[0];
  const int*   ei = (const int*)d_in[1];
  const float* W1 = (const float*)d_in[2];
  const float* b1 = (const float*)d_in[3];
  const float* W2 = (const float*)d_in[4];
  const float* b2 = (const float*)d_in[5];
  float* out = (float*)d_out;

  unsigned short* xbf = (unsigned short*)d_ws;               // 2,560,000 u16
  unsigned short* w1f = xbf + (size_t)NNODES * HID;          // 131,072 u16
  unsigned short* w2f = w1f + (size_t)131072;                // 4,096 u16
  unsigned short* Yb  = w2f + (size_t)4096;                  // 5,120,000 u16

  k_pack<<<1316, 256, 0, stream>>>(x, W1, W2, xbf, w1f, w2f);
  k_prep<<<dim3((NNODES + 31) / 32, 2), 256, 0, stream>>>(xbf, w1f, b1, Yb);
  k_edge<<<E_TOTAL / 64, 256, 0, stream>>>(ei, Yb, w2f, b2, out);
}

// Round 6
// 52.753 us; speedup vs baseline: 1.2861x; 1.2861x over previous
//
#include <hip/hip_runtime.h>

#define E_TOTAL 320000
#define NNODES  10000
#define HID     256
#define NCLS    10

typedef __attribute__((ext_vector_type(4))) float f32x4;
typedef __attribute__((ext_vector_type(2))) float f32x2;
typedef __attribute__((ext_vector_type(4))) unsigned int u32x4;
typedef __attribute__((ext_vector_type(8))) __bf16 bf16x8;
typedef __attribute__((ext_vector_type(8))) unsigned short u16x8;

static __device__ __forceinline__ unsigned short f2bf(float f) {
  unsigned u = __builtin_bit_cast(unsigned, f);
  u += 0x7fffu + ((u >> 16) & 1u);
  return (unsigned short)(u >> 16);
}

// ---- merged prep: x->bf16 | W1->frag | W2->frag, split by blockIdx ----
__global__ void k_pack(const float* __restrict__ x,
                       const float* __restrict__ W1,
                       const float* __restrict__ W2,
                       unsigned short* __restrict__ xbf,
                       unsigned short* __restrict__ w1f,
                       unsigned short* __restrict__ w2f) {
  int b = blockIdx.x, tid = threadIdx.x;
  if (b < 1250) {
    int i = b * 256 + tid;                        // one thread per 8 elems
    const f32x4* s = (const f32x4*)x + (size_t)i * 2;
    f32x4 a = s[0], c = s[1];
    u16x8 o;
    o[0]=f2bf(a[0]); o[1]=f2bf(a[1]); o[2]=f2bf(a[2]); o[3]=f2bf(a[3]);
    o[4]=f2bf(c[0]); o[5]=f2bf(c[1]); o[6]=f2bf(c[2]); o[7]=f2bf(c[3]);
    *((u16x8*)xbf + i) = o;
  } else if (b < 1314) {
    int gid = (b - 1250) * 256 + tid;             // 16384
    int l = gid & 63, kk = (gid >> 6) & 7, cb = (gid >> 9) & 15, half = gid >> 13;
    int kbase = half * 256 + kk * 32 + (l >> 4) * 8;
    int col = cb * 16 + (l & 15);
    u16x8 o;
#pragma unroll
    for (int j = 0; j < 8; ++j) o[j] = f2bf(W1[(size_t)(kbase + j) * HID + col]);
    *((u16x8*)w1f + gid) = o;
  } else {
    int gid = (b - 1314) * 256 + tid;             // 512
    int l = gid & 63, kk = gid >> 6;
    int kbase = kk * 32 + (l >> 4) * 8;
    int c = l & 15;
    u16x8 o;
#pragma unroll
    for (int j = 0; j < 8; ++j)
      o[j] = (c < NCLS) ? f2bf(W2[(size_t)(kbase + j) * NCLS + c]) : (unsigned short)0;
    *((u16x8*)w2f + gid) = o;
  }
}

// ---- node GEMM: Y = x@W1 (+b1 for half 0), output fp8-e4m3, fragment-permuted.
// Yf8[n][half*256 + pos(c)], pos(c) = ((c>>3)&3)*64 + ((c>>5)<<3) + (c&7)
// so that edge-kernel lane (row=l15, lhi) reads 64 CONTIGUOUS bytes at lhi*64.
__global__ __launch_bounds__(256, 3) void k_prep(
    const unsigned short* __restrict__ xbf,
    const unsigned short* __restrict__ w1f,
    const float* __restrict__ b1,
    unsigned char* __restrict__ Yf8)           // [NNODES][512] fp8
{
  __shared__ __align__(16) unsigned short ldsA[2][32 * 64];  // XOR-swizzled tiles

  const int tid  = threadIdx.x;
  const int lane = tid & 63;
  const int wv   = tid >> 6;
  const int n0   = blockIdx.x * 32;
  const int half = blockIdx.y;
  const int l15  = lane & 15;
  const int lhi  = lane >> 4;

  f32x4 acc[2][4] = {};

  auto stageA = [&](int kb, int buf) {
    int col0 = kb * 64;
    int r = wv * 8 + (lane >> 3);
    int gr = n0 + r; if (gr > NNODES - 1) gr = NNODES - 1;
    int usrc = (lane & 7) ^ (r & 7);
    const unsigned short* g = xbf + (size_t)gr * HID + col0 + usrc * 8;
    unsigned short* lp = &ldsA[buf][(wv * 8) * 64];
    __builtin_amdgcn_global_load_lds(
        (const __attribute__((address_space(1))) unsigned int*)g,
        (__attribute__((address_space(3))) unsigned int*)lp,
        16, 0, 0);
  };

  stageA(0, 0);

  for (int kb = 0; kb < 4; ++kb) {
    int buf = kb & 1;
    __syncthreads();
    if (kb < 3) stageA(kb + 1, buf ^ 1);

    bf16x8 bfr[2][4];
#pragma unroll
    for (int ks = 0; ks < 2; ++ks)
#pragma unroll
      for (int n = 0; n < 4; ++n) {
        int cb = wv * 4 + n;
        int kk = kb * 2 + ks;
        int f = (half * 16 + cb) * 8 + kk;
        bfr[ks][n] = *(const bf16x8*)(w1f + ((size_t)f * 64 + lane) * 8);
      }

#pragma unroll
    for (int ks = 0; ks < 2; ++ks) {
      bf16x8 afr[2];
#pragma unroll
      for (int m = 0; m < 2; ++m) {
        int row = m * 16 + l15;
        int boff = row * 128 + ((ks * 64 + lhi * 16) ^ ((row & 7) << 4));
        afr[m] = *(const bf16x8*)((const char*)&ldsA[buf][0] + boff);
      }
#pragma unroll
      for (int m = 0; m < 2; ++m)
#pragma unroll
        for (int n = 0; n < 4; ++n)
          acc[m][n] = __builtin_amdgcn_mfma_f32_16x16x32_bf16(afr[m], bfr[ks][n], acc[m][n], 0, 0, 0);
    }
  }

  float b1v[4];
#pragma unroll
  for (int n = 0; n < 4; ++n) b1v[n] = (half == 0) ? b1[wv * 64 + n * 16 + l15] : 0.f;

#pragma unroll
  for (int m = 0; m < 2; ++m)
#pragma unroll
    for (int n = 0; n < 4; ++n) {
      int col = wv * 64 + n * 16 + l15;
      int pos = ((col >> 3) & 3) * 64 + ((col >> 5) << 3) + (col & 7);
#pragma unroll
      for (int r = 0; r < 4; ++r) {
        int row = m * 16 + lhi * 4 + r;
        int gr = n0 + row;
        if (gr < NNODES) {
          float v = acc[m][n][r] + b1v[n];
          int pk = __builtin_amdgcn_cvt_pk_fp8_f32(v, v, 0, false);
          Yf8[(size_t)gr * 512 + half * 256 + pos] = (unsigned char)(pk & 0xff);
        }
      }
    }
}

// ---- edge kernel: gather fp8 Y1[src],Y2[dst] (256B each, 4 lines), decode,
// add+relu, bf16 GEMM2 (K=256,N=16pad), log_softmax.
__global__ __launch_bounds__(256, 4) void k_edge(
    const int* __restrict__ ei,
    const unsigned char* __restrict__ Yf8,
    const unsigned short* __restrict__ w2f,
    const float* __restrict__ b2,
    float* __restrict__ out)
{
  __shared__ __align__(16) unsigned short ldsW[4096];   // w2 frags, 8 KB

  const int tid  = threadIdx.x;
  const int lane = tid & 63;
  const int wv   = tid >> 6;
  const int e0   = blockIdx.x * 64;
  const int l15  = lane & 15;
  const int lhi  = lane >> 4;

  int edge = e0 + wv * 16 + l15;
  int src = ei[edge];
  int dst = ei[E_TOTAL + edge];

  // stage w2f -> LDS
  {
    const u16x8* s = (const u16x8*)w2f;
    u16x8* d = (u16x8*)ldsW;
    d[tid] = s[tid];
    d[tid + 256] = s[tid + 256];
  }
  __syncthreads();

  // per lane: 64 contiguous bytes per side (fragment-permuted fp8)
  const u32x4* q1 = (const u32x4*)(Yf8 + (size_t)src * 512 + lhi * 64);
  const u32x4* q2 = (const u32x4*)(Yf8 + (size_t)dst * 512 + 256 + lhi * 64);
  u32x4 ya[4], yb[4];
#pragma unroll
  for (int i = 0; i < 4; ++i) { ya[i] = q1[i]; yb[i] = q2[i]; }

  f32x4 lg = {0.f, 0.f, 0.f, 0.f};
#pragma unroll
  for (int kk = 0; kk < 8; ++kk) {
    bf16x8 bw = *(const bf16x8*)(ldsW + kk * 512 + lane * 8);
    unsigned a0 = ya[kk >> 1][(kk & 1) * 2], a1 = ya[kk >> 1][(kk & 1) * 2 + 1];
    unsigned c0 = yb[kk >> 1][(kk & 1) * 2], c1 = yb[kk >> 1][(kk & 1) * 2 + 1];
    f32x2 A0 = __builtin_amdgcn_cvt_pk_f32_fp8(a0, false);
    f32x2 A1 = __builtin_amdgcn_cvt_pk_f32_fp8(a0, true);
    f32x2 A2 = __builtin_amdgcn_cvt_pk_f32_fp8(a1, false);
    f32x2 A3 = __builtin_amdgcn_cvt_pk_f32_fp8(a1, true);
    f32x2 B0 = __builtin_amdgcn_cvt_pk_f32_fp8(c0, false);
    f32x2 B1 = __builtin_amdgcn_cvt_pk_f32_fp8(c0, true);
    f32x2 B2 = __builtin_amdgcn_cvt_pk_f32_fp8(c1, false);
    f32x2 B3 = __builtin_amdgcn_cvt_pk_f32_fp8(c1, true);
    bf16x8 hh;
    hh[0] = (__bf16)fmaxf(A0[0] + B0[0], 0.f);
    hh[1] = (__bf16)fmaxf(A0[1] + B0[1], 0.f);
    hh[2] = (__bf16)fmaxf(A1[0] + B1[0], 0.f);
    hh[3] = (__bf16)fmaxf(A1[1] + B1[1], 0.f);
    hh[4] = (__bf16)fmaxf(A2[0] + B2[0], 0.f);
    hh[5] = (__bf16)fmaxf(A2[1] + B2[1], 0.f);
    hh[6] = (__bf16)fmaxf(A3[0] + B3[0], 0.f);
    hh[7] = (__bf16)fmaxf(A3[1] + B3[1], 0.f);
    lg = __builtin_amdgcn_mfma_f32_16x16x32_bf16(hh, bw, lg, 0, 0, 0);
  }

  // + b2, log_softmax across the 16-lane class group (cols 10..15 padding)
  bool valid = (l15 < NCLS);
  float bias = valid ? b2[l15] : 0.f;
#pragma unroll
  for (int r = 0; r < 4; ++r) {
    float v = lg[r] + bias;
    float mv = valid ? v : -1e30f;
#pragma unroll
    for (int s = 1; s < 16; s <<= 1) mv = fmaxf(mv, __shfl_xor(mv, s, 64));
    float ev = valid ? __expf(v - mv) : 0.f;
    float sv = ev;
#pragma unroll
    for (int s = 1; s < 16; s <<= 1) sv += __shfl_xor(sv, s, 64);
    float res = v - mv - __logf(sv);
    if (valid) out[(size_t)(e0 + wv * 16 + lhi * 4 + r) * NCLS + l15] = res;
  }
}

extern "C" void kernel_launch(void* const* d_in, const int* in_sizes, int n_in,
                              void* d_out, int out_size, void* d_ws, size_t ws_size,
                              hipStream_t stream) {
  const float* x  = (const float*)d_in[0];
  const int*   ei = (const int*)d_in[1];
  const float* W1 = (const float*)d_in[2];
  const float* b1 = (const float*)d_in[3];
  const float* W2 = (const float*)d_in[4];
  const float* b2 = (const float*)d_in[5];
  float* out = (float*)d_out;

  unsigned short* xbf = (unsigned short*)d_ws;               // 2,560,000 u16
  unsigned short* w1f = xbf + (size_t)NNODES * HID;          // 131,072 u16
  unsigned short* w2f = w1f + (size_t)131072;                // 4,096 u16
  unsigned char*  Yf8 = (unsigned char*)(w2f + 4096);        // 5,120,000 B

  k_pack<<<1316, 256, 0, stream>>>(x, W1, W2, xbf, w1f, w2f);
  k_prep<<<dim3((NNODES + 31) / 32, 2), 256, 0, stream>>>(xbf, w1f, b1, Yf8);
  k_edge<<<E_TOTAL / 64, 256, 0, stream>>>(ei, Yf8, w2f, b2, out);
}